// Round 9
// baseline (49.689 us; speedup 1.0000x reference)
//
#include <hip/hip_runtime.h>
#include <hip/hip_bf16.h>

// ContrastiveLoss fused kernel for MI355X (gfx950).
//
// Math reduction (T=0.5):
//   f = x / max(||x||, 1e-8)   (rows)
//   s_ij = f_i . f_j
//   den_i = sum_{j: label_j != label_i} exp(2 s_ij)
//   loss  = sum_i [ c_i * log(den_i) - sum_{j same label, j != i} 2 s_ij ]
//           / (sum_i c_i + 1e-5),   c_i = count(label_i) - 1
//
// N=4096, D=512, labels in [0,100).
//
// Round 9: counted-vmcnt pipeline (T3/T4). Rounds 5-8 proved the 2-phase
// __syncthreads loop is the limiter (work halving didn't move time ->
// latency/drain-bound: each barrier embeds vmcnt(0) draining the staging
// just issued). New k2 inner loop: 16-row slabs (NJT=8), QUAD-buffered
// LDS (write target at iter t was last read at t-2, so ONE raw barrier
// per iter is race-free), stage slab t+2, then literal s_waitcnt
// vmcnt(8) (slab t's 4 loads forced-retired; in-order retirement) +
// raw s_barrier + sched_barrier(0). Tail: vmcnt(4)/vmcnt(0). Loop fully
// unrolled -> static buffer indices + waitcnt literals. Keeps round-8
// symmetric tile-pair decomposition (528 blocks) and fragment-major
// global/LDS layouts (conflict-free, fully coalesced).

typedef short short8 __attribute__((ext_vector_type(8)));
typedef float floatx4 __attribute__((ext_vector_type(4)));
typedef unsigned short u16;
typedef unsigned int u32;
typedef unsigned char u8;

#define N_ROWS 4096
#define DIM 512
#define GRPB 16384             // bytes per 16-row fragment group (16*1024)
#define EPS_NORM 1e-8f
#define EPS_DEN 1e-5f
#define TI 128                 // tile size (rows and cols)
#define NT (N_ROWS / TI)       // 32 tiles
#define NPAIR (NT * (NT + 1) / 2)   // 528 blocks
#define NJT 8                  // 8 slabs of 16 j-rows per tile

static __device__ inline u16 f32_to_bf16(float f) {
  u32 u = __float_as_uint(f);
  u32 r = (u + 0x7FFFu + ((u >> 16) & 1u)) >> 16;   // RNE
  return (u16)r;
}

static __device__ inline void load_lds16(const char* g, char* l) {
  __builtin_amdgcn_global_load_lds(
      (const __attribute__((address_space(1))) void*)g,
      (__attribute__((address_space(3))) void*)l, 16, 0, 0);
}

// wave-per-row normalize + bf16 pack, fragment-major store; grid 1024 x 256.
// G layout: group g = row>>4 (16 rows), chunk kt = k>>5 (32 elems), inside a
// 1 KB chunk lane l = kg*16 + (row&15) holds bytes [l*16, l*16+16) =
// elems k = kt*32 + kg*8 .. +8 of its row (the MFMA A/B fragment map).
__global__ void k1_normalize(const float* __restrict__ x,
                             const int* __restrict__ labels,
                             u16* __restrict__ G, u8* __restrict__ lab8,
                             float* __restrict__ den, float* __restrict__ pos,
                             float* __restrict__ acc2) {
  const int row = blockIdx.x * 4 + (threadIdx.x >> 6);
  const int lane = threadIdx.x & 63;
  const float4* src = reinterpret_cast<const float4*>(x + (size_t)row * DIM);
  float4 v0 = src[lane * 2];
  float4 v1 = src[lane * 2 + 1];
  float ss = v0.x*v0.x + v0.y*v0.y + v0.z*v0.z + v0.w*v0.w
           + v1.x*v1.x + v1.y*v1.y + v1.z*v1.z + v1.w*v1.w;
#pragma unroll
  for (int m = 1; m < 64; m <<= 1) ss += __shfl_xor(ss, m, 64);
  float scale = 1.f / fmaxf(sqrtf(ss), EPS_NORM);
  uint4 o;
  o.x = ((u32)f32_to_bf16(v0.y * scale) << 16) | (u32)f32_to_bf16(v0.x * scale);
  o.y = ((u32)f32_to_bf16(v0.w * scale) << 16) | (u32)f32_to_bf16(v0.z * scale);
  o.z = ((u32)f32_to_bf16(v1.y * scale) << 16) | (u32)f32_to_bf16(v1.x * scale);
  o.w = ((u32)f32_to_bf16(v1.w * scale) << 16) | (u32)f32_to_bf16(v1.z * scale);
  char* dst = (char*)G + (size_t)(row >> 4) * GRPB + (lane >> 2) * 1024
            + ((lane & 3) * 16 + (row & 15)) * 16;
  *reinterpret_cast<uint4*>(dst) = o;
  if (lane == 0) { den[row] = 0.f; pos[row] = 0.f; }
  if (lane == 1) lab8[row] = (u8)labels[row];
  if (blockIdx.x == 0 && threadIdx.x == 0) { acc2[0] = 0.f; acc2[1] = 0.f; }
}

// fused sim-GEMM + symmetric per-row/per-col reduction.
__global__ __launch_bounds__(256, 2) void k2_fused(
    const u16* __restrict__ G, const u8* __restrict__ lab8,
    float* __restrict__ den, float* __restrict__ pos) {
  // fragment-major B: 4 buffers x 16 chunks (kt) x 1 KB = 64 KB
  __shared__ u16 Bsh[4 * 16 * 512];
  __shared__ int labj_sh[TI];
  __shared__ float colden[TI], colpos[TI];

  const char* Gb = (const char*)G;
  char* bshb = (char*)Bsh;

  // decode pair (ti, tj), ti <= tj, from blockIdx
  int b = blockIdx.x;
  int ti = 0, rem = NT;
  while (b >= rem) { b -= rem; ++ti; --rem; }
  const int tj = ti + b;
  const bool diag = (ti == tj);

  const int tid = threadIdx.x;
  const int wv = tid >> 6;
  const int lane = tid & 63;
  const int l15 = lane & 15;
  const int kg = lane >> 4;               // 0..3

  const int ib = ti * TI;
  const int jb = tj * TI;

  // stage one 16-row B slab (1 fragment group) into LDS buffer bufsel;
  // wave wv stages chunks wv*4 .. wv*4+3 (contiguous 1 KB src AND dst).
#define STAGE(bufsel, slab) do {                                            \
    _Pragma("unroll")                                                       \
    for (int i_ = 0; i_ < 4; ++i_) {                                        \
      const int c_ = wv * 4 + i_;                                           \
      load_lds16(Gb + (size_t)(tj * 8 + (slab)) * GRPB + c_ * 1024 + lane * 16, \
                 bshb + (bufsel) * 16384 + c_ * 1024 + lane * 16);          \
    }                                                                       \
  } while (0)

  // prologue: stage slabs 0,1 into bufs 0,1; labels + col accs into LDS
  STAGE(0, 0);
  STAGE(1, 1);
  if (tid < TI) {
    labj_sh[tid] = lab8[jb + tid];
    colden[tid] = 0.f;
    colpos[tid] = 0.f;
  }

  // A fragments: 32 rows/wave = 2 fragment groups, K=512, register-resident.
  short8 a[2][16];
#pragma unroll
  for (int s = 0; s < 2; ++s) {
    const char* abase = Gb + (size_t)(ti * 8 + wv * 2 + s) * GRPB + lane * 16;
#pragma unroll
    for (int kt = 0; kt < 16; ++kt)
      a[s][kt] = *reinterpret_cast<const short8*>(abase + kt * 1024);
  }
  // pin A in VGPRs (round-1 pathology: compiler sank loads into the loop)
#pragma unroll
  for (int s = 0; s < 2; ++s)
#pragma unroll
    for (int kt = 0; kt < 16; ++kt)
      asm volatile("" : "+v"(a[s][kt]));

  // C/D layout (verified gfx950): col = lane&15 (j), row = kg*4 + r (i).
  const int i_base = ib + wv * 32 + kg * 4;
  const u32 labp0 = *reinterpret_cast<const u32*>(lab8 + i_base);
  const u32 labp1 = *reinterpret_cast<const u32*>(lab8 + i_base + 16);

  float den_acc[2][4] = {{0.f,0.f,0.f,0.f},{0.f,0.f,0.f,0.f}};
  float pos_acc[2][4] = {{0.f,0.f,0.f,0.f},{0.f,0.f,0.f,0.f}};

  __syncthreads();   // labels/col ready (also drains prologue; one-time)

  // counted-vmcnt pipeline, fully unrolled: iter t consumes slab t (buf t&3),
  // stages slab t+2 (buf (t+2)&3). Quad buffer => the written buffer was
  // last read at iter t-2, fenced by iter t-1's barrier: single barrier/iter
  // is race-free. vmcnt(8) = slabs t+1,t+2 in flight; slab t forced retired.
#pragma unroll
  for (int t = 0; t < NJT; ++t) {
    if (t + 2 < NJT) STAGE((t + 2) & 3, t + 2);

    if (t < NJT - 2)      asm volatile("s_waitcnt vmcnt(8)" ::: "memory");
    else if (t == NJT - 2) asm volatile("s_waitcnt vmcnt(4)" ::: "memory");
    else                   asm volatile("s_waitcnt vmcnt(0)" ::: "memory");
    __builtin_amdgcn_s_barrier();
    __builtin_amdgcn_sched_barrier(0);

    const int jrow = jb + t * 16 + l15;
    const int labj = labj_sh[t * 16 + l15];

    floatx4 acc0 = {0.f,0.f,0.f,0.f};
    floatx4 acc1 = {0.f,0.f,0.f,0.f};
    const char* bbase = bshb + (t & 3) * 16384 + lane * 16;
#pragma unroll
    for (int kt = 0; kt < 16; ++kt) {
      short8 bk = *reinterpret_cast<const short8*>(bbase + kt * 1024);
      acc0 = __builtin_amdgcn_mfma_f32_16x16x32_bf16(a[0][kt], bk, acc0, 0, 0, 0);
      acc1 = __builtin_amdgcn_mfma_f32_16x16x32_bf16(a[1][kt], bk, acc1, 0, 0, 0);
    }

    float cd = 0.f, cp = 0.f;   // col partials for this 16-j slab
#pragma unroll
    for (int s = 0; s < 2; ++s) {
      floatx4 av = s ? acc1 : acc0;
      const u32 labp = s ? labp1 : labp0;
#pragma unroll
      for (int r = 0; r < 4; ++r) {
        const int labi = (int)((labp >> (8 * r)) & 255u);
        const int irow = i_base + s * 16 + r;
        float s2 = 2.f * av[r];
        float e = __expf(s2);
        bool sm = (labj == labi);
        float dv = sm ? 0.f : e;
        float pv = (sm && (jrow != irow)) ? s2 : 0.f;
        den_acc[s][r] += dv;
        pos_acc[s][r] += pv;
        cd += dv; cp += pv;
      }
    }
    if (!diag) {
      // reduce col partials across the 4 kg groups (lanes sharing l15)
      cd += __shfl_xor(cd, 16, 64); cd += __shfl_xor(cd, 32, 64);
      cp += __shfl_xor(cp, 16, 64); cp += __shfl_xor(cp, 32, 64);
      if (kg == 0) {
        atomicAdd(&colden[t * 16 + l15], cd);
        atomicAdd(&colpos[t * 16 + l15], cp);
      }
    }
  }

  // row path: reduce across the 16 cols (lanes with same kg), 1 atomic/row
#pragma unroll
  for (int s = 0; s < 2; ++s)
#pragma unroll
    for (int r = 0; r < 4; ++r) {
      float dd = den_acc[s][r], p = pos_acc[s][r];
#pragma unroll
      for (int m = 1; m < 16; m <<= 1) {
        dd += __shfl_xor(dd, m, 64);
        p += __shfl_xor(p, m, 64);
      }
      if (l15 == 0) {
        atomicAdd(&den[i_base + s * 16 + r], dd);
        atomicAdd(&pos[i_base + s * 16 + r], p);
      }
    }

  // col path flush (off-diagonal blocks): one atomic per col
  if (!diag) {
    __syncthreads();   // all waves' LDS col atomics done
    if (tid < TI) {
      atomicAdd(&den[jb + tid], colden[tid]);
      atomicAdd(&pos[jb + tid], colpos[tid]);
    }
  }
#undef STAGE
}

// per-row finalize, 16 blocks x 256 threads; block partial -> global atomics
__global__ void k3a(const float* __restrict__ den, const float* __restrict__ pos,
                    const int* __restrict__ labels, float* __restrict__ acc2) {
  __shared__ int hist[128];
  __shared__ float sn[4], sz[4];
  const int tid = threadIdx.x;
  if (tid < 128) hist[tid] = 0;
  __syncthreads();
  for (int i = tid; i < N_ROWS; i += 256) atomicAdd(&hist[labels[i]], 1);
  __syncthreads();

  const int row = blockIdx.x * 256 + tid;
  int c = hist[labels[row]] - 1;
  float num = (float)c * logf(den[row]) - pos[row];
  float nnz = (float)c;
#pragma unroll
  for (int m = 1; m < 64; m <<= 1) {
    num += __shfl_xor(num, m, 64);
    nnz += __shfl_xor(nnz, m, 64);
  }
  if ((tid & 63) == 0) { sn[tid >> 6] = num; sz[tid >> 6] = nnz; }
  __syncthreads();
  if (tid == 0) {
    atomicAdd(&acc2[0], sn[0] + sn[1] + sn[2] + sn[3]);
    atomicAdd(&acc2[1], sz[0] + sz[1] + sz[2] + sz[3]);
  }
}

__global__ void k3b(const float* __restrict__ acc2, float* __restrict__ out) {
  out[0] = acc2[0] / (acc2[1] + EPS_DEN);
}

extern "C" void kernel_launch(void* const* d_in, const int* in_sizes, int n_in,
                              void* d_out, int out_size, void* d_ws, size_t ws_size,
                              hipStream_t stream) {
  const float* x = (const float*)d_in[0];
  const int* labels = (const int*)d_in[1];

  // ws: G (4MB) | den f32[4096] | pos f32[4096] | lab8 u8[4096] | acc2 f32[2]
  u16* G = (u16*)d_ws;
  float* den = (float*)((char*)d_ws + (size_t)N_ROWS * DIM * 2);
  float* pos = den + N_ROWS;
  u8* lab8 = (u8*)(pos + N_ROWS);
  float* acc2 = (float*)(lab8 + N_ROWS);
  float* out = (float*)d_out;

  hipLaunchKernelGGL(k1_normalize, dim3(N_ROWS / 4), dim3(256), 0, stream,
                     x, labels, G, lab8, den, pos, acc2);
  hipLaunchKernelGGL(k2_fused, dim3(NPAIR), dim3(256), 0, stream,
                     G, lab8, den, pos);
  hipLaunchKernelGGL(k3a, dim3(16), dim3(256), 0, stream,
                     den, pos, labels, acc2);
  hipLaunchKernelGGL(k3b, dim3(1), dim3(1), 0, stream, acc2, out);
}